// Round 17
// baseline (3997.425 us; speedup 1.0000x reference)
//
#include <hip/hip_runtime.h>
#include <hip/hip_bf16.h>

// GRU restructured (v17): per-wave flag barrier (decentralized).
//   - 128 flags/group (one per WAVE). Each wave: asm s_waitcnt vmcnt(0)
//     lgkmcnt(0) (drains ONLY its own stores/LDS reads) -> lane-0 relaxed
//     agent flag store -> prefetch -> poll 128 slots (2 per lane). The two
//     block-wide barrier-entry __syncthreads per step are DELETED; hx WAR
//     hazards are closed by the poll (sibling flag >= target implies its
//     lgkm drain, i.e. its MFMA ds_reads finished). zL/RED hazards remain
//     covered by the staging/RED syncs (audited per hazard).
//   - converts fused into one kernel (3 fewer launches).
//   proj3/out_gemm (M=128 tiles) and the rest unchanged from v16.

#define EMB 512
#define HID 1024
#define BATCHN 64
#define TLEN 512
#define CAT 1536
#define GROUPS 4
#define GB 16
#define WPG 32            // WGs per group (each owns 32 cols)
#define HX_LD 1024        // swizzled layout, no pad needed
#define ZL_LD 34
#define GPAD 8

typedef __attribute__((ext_vector_type(8))) short bf16x8;
typedef __attribute__((ext_vector_type(4))) short s16x4;
typedef __attribute__((ext_vector_type(4))) float f32x4;
typedef unsigned int u32;
typedef unsigned long long u64;
typedef unsigned short u16;

__device__ __forceinline__ float bf2f(u16 u) {
  union { float f; u32 i; } v; v.i = ((u32)u) << 16; return v.f;
}
__device__ __forceinline__ u16 f2bf(float f) {
  union { float f; u32 i; } v; v.f = f;
  u32 r = v.i + 0x7fffu + ((v.i >> 16) & 1u);
  return (u16)(r >> 16);
}

// Agent-scope relaxed atomics (verified primitives, v4-v16).
__device__ __forceinline__ u64 ld_dc(const u16* p) {
  return __hip_atomic_load((const u64*)p, __ATOMIC_RELAXED, __HIP_MEMORY_SCOPE_AGENT);
}
__device__ __forceinline__ void st_dc16(u16* p, u16 v) {
  __hip_atomic_store(p, v, __ATOMIC_RELAXED, __HIP_MEMORY_SCOPE_AGENT);
}

// ---------------- phase 0: fused weight conversion ----------------
__global__ __launch_bounds__(256) void convert_all(
    const float* __restrict__ Wz, const float* __restrict__ Wr,
    const float* __restrict__ Wh, const float* __restrict__ Wy,
    u16* __restrict__ Wzh, u16* __restrict__ Wzx,
    u16* __restrict__ Wrh, u16* __restrict__ Wrx,
    u16* __restrict__ Whh, u16* __restrict__ Whx, u16* __restrict__ WyB) {
  int i = blockIdx.x * 256 + threadIdx.x;
  if (i < HID * CAT) {
    int row = i / CAT, col = i - row * CAT;
    u16 vz = f2bf(Wz[i]), vr = f2bf(Wr[i]), vh = f2bf(Wh[i]);
    if (col < HID) {
      Wzh[row * HID + col] = vz;
      Wrh[row * HID + col] = vr;
      Whh[row * HID + col] = vh;
    } else {
      int c = col - HID;
      Wzx[row * EMB + c] = vz;
      Wrx[row * EMB + c] = vr;
      Whx[row * EMB + c] = vh;
    }
  }
  if (i < EMB * HID) WyB[i] = f2bf(Wy[i]);
}

// -------- phase 1 (fused, M=128): Pg = shift(word) @ Wg_x.T + bg --------
__global__ __launch_bounds__(256) void proj3_kernel(
    const float* __restrict__ word,
    const u16* __restrict__ Wzx, const u16* __restrict__ Wrx, const u16* __restrict__ Whx,
    const float* __restrict__ bz, const float* __restrict__ br, const float* __restrict__ bh,
    u16* __restrict__ Pz, u16* __restrict__ Pr, u16* __restrict__ Ph) {
  __shared__ __align__(16) u16 As[128][64 + GPAD];
  __shared__ __align__(16) u16 Bs[3][64][64 + GPAD];
  const int tid = threadIdx.x;
  const int wid = tid >> 6, lane = tid & 63;
  const int m0 = blockIdx.x * 128, n0 = blockIdx.y * 64;
  const int mw = wid * 32;  // each wave owns 32 rows x 64 cols
  const u16* __restrict__ Wx[3] = {Wzx, Wrx, Whx};
  f32x4 acc[3][2][4] = {};
  for (int k0 = 0; k0 < EMB; k0 += 64) {
#pragma unroll
    for (int it = 0; it < 8; ++it) {
      int e = (it * 256 + tid) * 4;
      int row = e >> 6, col = e & 63;
      int R = m0 + row;
      float4 a = make_float4(0.f, 0.f, 0.f, 0.f);
      if ((R & (TLEN - 1)) != 0)
        a = *reinterpret_cast<const float4*>(&word[(u64)(R - 1) * EMB + k0 + col]);
      s16x4 vv;
      vv[0] = (short)f2bf(a.x); vv[1] = (short)f2bf(a.y);
      vv[2] = (short)f2bf(a.z); vv[3] = (short)f2bf(a.w);
      *reinterpret_cast<s16x4*>(&As[row][col]) = vv;
    }
#pragma unroll
    for (int p = 0; p < 3; ++p)
#pragma unroll
      for (int it = 0; it < 2; ++it) {
        int e = (it * 256 + tid) * 8;
        int row = e >> 6, col = e & 63;
        *reinterpret_cast<bf16x8*>(&Bs[p][row][col]) =
            *reinterpret_cast<const bf16x8*>(&Wx[p][(u64)(n0 + row) * EMB + k0 + col]);
      }
    __syncthreads();
#pragma unroll
    for (int kk = 0; kk < 2; ++kk) {
      const int kb = kk * 32 + 8 * (lane >> 4);
#pragma unroll
      for (int i = 0; i < 2; ++i) {
        bf16x8 a = *reinterpret_cast<const bf16x8*>(&As[mw + i * 16 + (lane & 15)][kb]);
#pragma unroll
        for (int p = 0; p < 3; ++p)
#pragma unroll
          for (int j = 0; j < 4; ++j) {
            bf16x8 b = *reinterpret_cast<const bf16x8*>(&Bs[p][j * 16 + (lane & 15)][kb]);
            acc[p][i][j] = __builtin_amdgcn_mfma_f32_16x16x32_bf16(a, b, acc[p][i][j], 0, 0, 0);
          }
      }
    }
    __syncthreads();
  }
  u16* __restrict__ Pout[3] = {Pz, Pr, Ph};
  const float* __restrict__ bias[3] = {bz, br, bh};
#pragma unroll
  for (int p = 0; p < 3; ++p)
#pragma unroll
    for (int i = 0; i < 2; ++i)
#pragma unroll
      for (int j = 0; j < 4; ++j) {
        int col = n0 + j * 16 + (lane & 15);
        float bv = bias[p][col];
#pragma unroll
        for (int q = 0; q < 4; ++q) {
          int row = m0 + mw + i * 16 + 4 * (lane >> 4) + q;
          Pout[p][(u64)row * HID + col] = f2bf(acc[p][i][j][q] + bv);
        }
      }
}

// ---------------- phase 3 (M=128): out = H @ Wy.T + by (fp32 out) ----------------
__global__ __launch_bounds__(256) void out_gemm(const u16* __restrict__ H,
                                                const u16* __restrict__ Wy,
                                                const float* __restrict__ by,
                                                float* __restrict__ out) {
  __shared__ __align__(16) u16 As[128][64 + GPAD];
  __shared__ __align__(16) u16 Bs[64][64 + GPAD];
  const int tid = threadIdx.x;
  const int wid = tid >> 6, lane = tid & 63;
  const int m0 = blockIdx.x * 128, n0 = blockIdx.y * 64;
  const int mw = wid * 32;  // each wave: 32 rows x 64 cols
  f32x4 acc[2][4] = {};
  for (int k0 = 0; k0 < HID; k0 += 64) {
#pragma unroll
    for (int it = 0; it < 4; ++it) {
      int e = (it * 256 + tid) * 8;
      int row = e >> 6, col = e & 63;
      *reinterpret_cast<bf16x8*>(&As[row][col]) =
          *reinterpret_cast<const bf16x8*>(&H[(u64)(m0 + row) * HID + k0 + col]);
    }
#pragma unroll
    for (int it = 0; it < 2; ++it) {
      int e = (it * 256 + tid) * 8;
      int row = e >> 6, col = e & 63;
      *reinterpret_cast<bf16x8*>(&Bs[row][col]) =
          *reinterpret_cast<const bf16x8*>(&Wy[(u64)(n0 + row) * HID + k0 + col]);
    }
    __syncthreads();
#pragma unroll
    for (int kk = 0; kk < 2; ++kk) {
      const int kb = kk * 32 + 8 * (lane >> 4);
#pragma unroll
      for (int i = 0; i < 2; ++i) {
        bf16x8 a = *reinterpret_cast<const bf16x8*>(&As[mw + i * 16 + (lane & 15)][kb]);
#pragma unroll
        for (int j = 0; j < 4; ++j) {
          bf16x8 b = *reinterpret_cast<const bf16x8*>(&Bs[j * 16 + (lane & 15)][kb]);
          acc[i][j] = __builtin_amdgcn_mfma_f32_16x16x32_bf16(a, b, acc[i][j], 0, 0, 0);
        }
      }
    }
    __syncthreads();
  }
#pragma unroll
  for (int i = 0; i < 2; ++i)
#pragma unroll
    for (int j = 0; j < 4; ++j) {
      int col = n0 + j * 16 + (lane & 15);
      float bv = by[col];
#pragma unroll
      for (int q = 0; q < 4; ++q) {
        int row = m0 + mw + i * 16 + 4 * (lane >> 4) + q;
        out[(u64)row * EMB + col] = acc[i][j][q] + bv;
      }
    }
}

// ---------------- phase 2: persistent recurrent kernel ----------------
// Poll 128 per-wave flags: each lane polls 2 slots.
__device__ __forceinline__ void poll_flags128(u32* gflags, u32 target) {
  const int lane = threadIdx.x & 63;
  u32* a0 = &gflags[lane * 16];
  u32* a1 = &gflags[(lane + 64) * 16];
  for (;;) {
    u32 v0 = __hip_atomic_load(a0, __ATOMIC_RELAXED, __HIP_MEMORY_SCOPE_AGENT);
    u32 v1 = __hip_atomic_load(a1, __ATOMIC_RELAXED, __HIP_MEMORY_SCOPE_AGENT);
    if (!__any((int)((v0 < target) | (v1 < target)))) break;
  }
}

__global__ __launch_bounds__(256, 1) void gru_persistent(
    const u16* __restrict__ Wzh, const u16* __restrict__ Wrh, const u16* __restrict__ Whh,
    const u16* __restrict__ Pz, const u16* __restrict__ Pr, u16* __restrict__ PhH,
    u16* __restrict__ rhbuf, u32* flags) {
  // LDS ~34.8 KB: hx (coop-load staging, swizzled) + zL + RED.
  __shared__ __align__(16) u16 hx[16 * HX_LD];
  __shared__ __align__(16) u16 zL[16 * ZL_LD];
  __shared__ __align__(16) float RED[4 * 64 * 4];

  const int tid = threadIdx.x;
  const int wid = tid >> 6;
  const int lane = tid & 63;
  const int l15 = lane & 15;
  const int k4 = lane >> 4;  // 0..3
  const int g = blockIdx.x & (GROUPS - 1);
  const int w = blockIdx.x >> 2;  // 0..31, owns cols [32w, 32w+32)
  const int b0 = g * GB;
  const int j = wid & 1;        // 16-col tile within the 32
  const int gate = wid >> 1;    // stage A: 0 = z, 1 = r
  const int kh = wid >> 1;      // stage B: K-half
  const int colA = 32 * w + 16 * j + l15;
  const u16* __restrict__ PA = gate ? Pr : Pz;
  u32* gflags = flags + g * (128 * 16);
  u32* myflag = &gflags[(w * 4 + wid) * 16];

  // hx XOR swizzle: element offset e in row r maps to e ^ ((r&7)<<3).
  const int sw = (l15 & 7) << 3;
  const int srow = tid >> 4;
  const int soff = (tid & 15) * 4;
  const int ssw = (srow & 7) << 3;

  // ---- weights -> registers, PINNED (asm "+v" blocks rematerialization) ----
  bf16x8 wfA[32];  // 16 cols of Wzh (waves 0-1) or Wrh (waves 2-3), full K
#pragma unroll
  for (int s = 0; s < 32; ++s)
    wfA[s] = *reinterpret_cast<const bf16x8*>(
        (gate ? Wrh : Wzh) + (u64)colA * HID + 32 * s + k4 * 8);
  bf16x8 wfB[16];  // 16 cols of Whh, K-half kh
#pragma unroll
  for (int s = 0; s < 16; ++s)
    wfB[s] = *reinterpret_cast<const bf16x8*>(
        Whh + (u64)colA * HID + kh * 512 + 32 * s + k4 * 8);
#pragma unroll
  for (int s = 0; s < 32; ++s) asm volatile("" : "+v"(wfA[s]));
#pragma unroll
  for (int s = 0; s < 16; ++s) asm volatile("" : "+v"(wfB[s]));

  // zero hx (h(-1) = 0; swizzle-invariant)
  for (int e = tid; e < 16 * HX_LD / 2; e += 256) reinterpret_cast<u32*>(hx)[e] = 0u;
  __syncthreads();

  // prefetched P values — RAW u16 (convert at use; waits sink to use point)
  u16 pAr[4], pBr[4];
#pragma unroll
  for (int q = 0; q < 4; ++q) {
    int m = 4 * k4 + q;
    pAr[q] = PA[((u64)(b0 + m) * TLEN) * HID + colA];
    pBr[q] = PhH[((u64)(b0 + m) * TLEN) * HID + colA];
  }

  float hprev[4] = {0.f, 0.f, 0.f, 0.f};  // h(t-1) at (4*k4+q, colA), ALL waves
  u32 ph = 0;

  for (int t = 0; t < TLEN; ++t) {
    // ---- cooperative load h(t-1) -> hx (batched agent u64 loads) ----
    if (t > 0) {
      const u16* src = PhH + ((u64)(b0 + srow) * TLEN + (t - 1)) * HID + soff;
      u64 tmp[16];
#pragma unroll
      for (int i = 0; i < 16; ++i) tmp[i] = ld_dc(src + i * 64);
      u16* dst = &hx[srow * HX_LD];
#pragma unroll
      for (int i = 0; i < 16; ++i)
        *reinterpret_cast<u64*>(dst + ((soff + i * 64) ^ ssw)) = tmp[i];
      __syncthreads();  // staging complete before MFMA reads
    }

    // ================= phase A: z,r = sigmoid(h @ W.T + P) =================
    f32x4 acc = {0.f, 0.f, 0.f, 0.f}, acc_b = {0.f, 0.f, 0.f, 0.f};
    if (t > 0) {
#pragma unroll
      for (int s = 0; s < 32; s += 2) {
        bf16x8 a0 = *reinterpret_cast<const bf16x8*>(
            &hx[l15 * HX_LD + ((32 * s + k4 * 8) ^ sw)]);
        bf16x8 a1 = *reinterpret_cast<const bf16x8*>(
            &hx[l15 * HX_LD + ((32 * (s + 1) + k4 * 8) ^ sw)]);
        acc   = __builtin_amdgcn_mfma_f32_16x16x32_bf16(a0, wfA[s],     acc,   0, 0, 0);
        acc_b = __builtin_amdgcn_mfma_f32_16x16x32_bf16(a1, wfA[s + 1], acc_b, 0, 0, 0);
      }
    }
#pragma unroll
    for (int q = 0; q < 4; ++q) {
      int m = 4 * k4 + q;
      float pre = acc[q] + acc_b[q] + bf2f(pAr[q]);
      float sg = 1.f / (1.f + __expf(-pre));
      if (gate == 0) {
        zL[m * ZL_LD + 16 * j + l15] = f2bf(sg);
      } else {
        st_dc16(rhbuf + (u64)(g * GB + m) * HID + colA, f2bf(sg * hprev[q]));
      }
    }

    // ---- wave barrier A: own drain -> per-wave flag -> prefetch -> poll ----
    ++ph;
    asm volatile("s_waitcnt vmcnt(0) lgkmcnt(0)" ::: "memory");
    if (lane == 0)
      __hip_atomic_store(myflag, ph, __ATOMIC_RELAXED, __HIP_MEMORY_SCOPE_AGENT);
    {
      int tn = (t + 1 < TLEN) ? (t + 1) : t;
#pragma unroll
      for (int q = 0; q < 4; ++q) {
        int m = 4 * k4 + q;
        pAr[q] = PA[((u64)(b0 + m) * TLEN + tn) * HID + colA];  // raw, no wait
      }
    }
    poll_flags128(gflags, ph);
    asm volatile("" ::: "memory");

    // ---- cooperative load rh -> hx (poll released this wave; WAR closed
    //      because every sibling's flag implies its lgkm drain = reads done) ----
    {
      const u16* src = rhbuf + (u64)(g * GB + srow) * HID + soff;
      u64 tmp[16];
#pragma unroll
      for (int i = 0; i < 16; ++i) tmp[i] = ld_dc(src + i * 64);
      u16* dst = &hx[srow * HX_LD];
#pragma unroll
      for (int i = 0; i < 16; ++i)
        *reinterpret_cast<u64*>(dst + ((soff + i * 64) ^ ssw)) = tmp[i];
      __syncthreads();  // staging complete before MFMA reads
    }

    // ========= phase B: htilde = tanh(rh @ Whh.T + Ph); h update =========
    f32x4 acc2 = {0.f, 0.f, 0.f, 0.f}, acc2b = {0.f, 0.f, 0.f, 0.f};
#pragma unroll
    for (int s = 0; s < 16; s += 2) {
      bf16x8 a0 = *reinterpret_cast<const bf16x8*>(
          &hx[l15 * HX_LD + ((kh * 512 + 32 * s + k4 * 8) ^ sw)]);
      bf16x8 a1 = *reinterpret_cast<const bf16x8*>(
          &hx[l15 * HX_LD + ((kh * 512 + 32 * (s + 1) + k4 * 8) ^ sw)]);
      acc2  = __builtin_amdgcn_mfma_f32_16x16x32_bf16(a0, wfB[s],     acc2,  0, 0, 0);
      acc2b = __builtin_amdgcn_mfma_f32_16x16x32_bf16(a1, wfB[s + 1], acc2b, 0, 0, 0);
    }
#pragma unroll
    for (int q = 0; q < 4; ++q) acc2[q] += acc2b[q];
    // exchange K-half partials; ALL waves compute identical h (add commutes)
    *reinterpret_cast<f32x4*>(&RED[(wid * 64 + lane) * 4]) = acc2;
    __syncthreads();
    {
      f32x4 part = *reinterpret_cast<const f32x4*>(&RED[((wid ^ 2) * 64 + lane) * 4]);
#pragma unroll
      for (int q = 0; q < 4; ++q) {
        int m = 4 * k4 + q;
        float pre = acc2[q] + part[q] + bf2f(pBr[q]);
        float e2 = __expf(2.f * pre);
        float th = 1.f - 2.f / (e2 + 1.f);  // tanh, inf-safe
        float zq = bf2f(zL[m * ZL_LD + 16 * j + l15]);
        float hn = (1.f - zq) * hprev[q] + zq * th;
        hprev[q] = hn;
        if (wid < 2)  // direct store h(t) -> PhH[t] (in-place over Ph)
          st_dc16(PhH + ((u64)(b0 + m) * TLEN + t) * HID + colA, f2bf(hn));
      }
    }

    // ---- wave barrier B: own drain -> per-wave flag -> prefetch -> poll ----
    ++ph;
    asm volatile("s_waitcnt vmcnt(0) lgkmcnt(0)" ::: "memory");
    if (lane == 0)
      __hip_atomic_store(myflag, ph, __ATOMIC_RELAXED, __HIP_MEMORY_SCOPE_AGENT);
    {
      int tn = (t + 1 < TLEN) ? (t + 1) : t;
#pragma unroll
      for (int q = 0; q < 4; ++q) {
        int m = 4 * k4 + q;
        pBr[q] = PhH[((u64)(b0 + m) * TLEN + tn) * HID + colA];  // raw, no wait
      }
    }
    poll_flags128(gflags, ph);
    asm volatile("" ::: "memory");
  }
}

// ---------------- host ----------------
extern "C" void kernel_launch(void* const* d_in, const int* in_sizes, int n_in,
                              void* d_out, int out_size, void* d_ws, size_t ws_size,
                              hipStream_t stream) {
  const float* word = (const float*)d_in[0];
  const float* Wz = (const float*)d_in[1];
  const float* bz = (const float*)d_in[2];
  const float* Wr = (const float*)d_in[3];
  const float* br = (const float*)d_in[4];
  const float* Wh = (const float*)d_in[5];
  const float* bh = (const float*)d_in[6];
  const float* Wy = (const float*)d_in[7];
  const float* by = (const float*)d_in[8];
  float* out = (float*)d_out;
  (void)in_sizes; (void)n_in; (void)out_size; (void)ws_size;

  char* ws = (char*)d_ws;
  size_t off = 0;
  auto alloc = [&](size_t bytes) {
    char* p = ws + off;
    off += (bytes + 255) & ~(size_t)255;
    return p;
  };
  u32* flags = (u32*)alloc(GROUPS * 128 * 16 * sizeof(u32));  // 32 KB
  u16* WzhB = (u16*)alloc((size_t)HID * HID * 2);
  u16* WrhB = (u16*)alloc((size_t)HID * HID * 2);
  u16* WhhB = (u16*)alloc((size_t)HID * HID * 2);
  u16* WzxB = (u16*)alloc((size_t)HID * EMB * 2);
  u16* WrxB = (u16*)alloc((size_t)HID * EMB * 2);
  u16* WhxB = (u16*)alloc((size_t)HID * EMB * 2);
  u16* WyB  = (u16*)alloc((size_t)EMB * HID * 2);
  u16* Pr   = (u16*)alloc((size_t)BATCHN * TLEN * HID * 2);
  u16* PhH  = (u16*)alloc((size_t)BATCHN * TLEN * HID * 2);
  u16* rhbuf = (u16*)alloc((size_t)GROUPS * GB * HID * 2);
  // total ws use ~138 MiB
  u16* Pz = (u16*)d_out;  // overlay: 32768x1024 bf16 == 32768x512 fp32; dead
                          // before out_gemm overwrites d_out.

  hipMemsetAsync(flags, 0, GROUPS * 128 * 16 * sizeof(u32), stream);

  convert_all<<<(HID * CAT + 255) / 256, 256, 0, stream>>>(
      Wz, Wr, Wh, Wy, WzhB, WzxB, WrhB, WrxB, WhhB, WhxB, WyB);

  proj3_kernel<<<dim3(256, 16), 256, 0, stream>>>(word, WzxB, WrxB, WhxB,
                                                  bz, br, bh, Pz, Pr, PhH);

  gru_persistent<<<dim3(GROUPS * WPG), dim3(256), 0, stream>>>(WzhB, WrhB, WhhB, Pz, Pr, PhH,
                                                               rhbuf, flags);

  out_gemm<<<dim3(256, 8), 256, 0, stream>>>(PhH, WyB, by, out);
}

// Round 18
// 2856.535 us; speedup vs baseline: 1.3994x; 1.3994x over previous
//
#include <hip/hip_runtime.h>
#include <hip/hip_bf16.h>

// GRU restructured (v18): REVERT v17's per-wave-flag regression (3655us) back
// to the proven v15/v16 protocol (gru ~2523-2545us): 32 per-WG flags, drain
// __syncthreads before flag store, all-wave 32-slot poll, raw-u16 prefetch in
// the barrier window. Keeps v16's M=128 GEMM tiles and v17's fused convert_all
// (independently good). This is the best-known configuration of all parts.

#define EMB 512
#define HID 1024
#define BATCHN 64
#define TLEN 512
#define CAT 1536
#define GROUPS 4
#define GB 16
#define WPG 32            // WGs per group (each owns 32 cols)
#define HX_LD 1024        // swizzled layout, no pad needed
#define ZL_LD 34
#define GPAD 8

typedef __attribute__((ext_vector_type(8))) short bf16x8;
typedef __attribute__((ext_vector_type(4))) short s16x4;
typedef __attribute__((ext_vector_type(4))) float f32x4;
typedef unsigned int u32;
typedef unsigned long long u64;
typedef unsigned short u16;

__device__ __forceinline__ float bf2f(u16 u) {
  union { float f; u32 i; } v; v.i = ((u32)u) << 16; return v.f;
}
__device__ __forceinline__ u16 f2bf(float f) {
  union { float f; u32 i; } v; v.f = f;
  u32 r = v.i + 0x7fffu + ((v.i >> 16) & 1u);
  return (u16)(r >> 16);
}

// Agent-scope relaxed atomics (verified primitives, v4-v16).
__device__ __forceinline__ u64 ld_dc(const u16* p) {
  return __hip_atomic_load((const u64*)p, __ATOMIC_RELAXED, __HIP_MEMORY_SCOPE_AGENT);
}
__device__ __forceinline__ void st_dc16(u16* p, u16 v) {
  __hip_atomic_store(p, v, __ATOMIC_RELAXED, __HIP_MEMORY_SCOPE_AGENT);
}

// ---------------- phase 0: fused weight conversion ----------------
__global__ __launch_bounds__(256) void convert_all(
    const float* __restrict__ Wz, const float* __restrict__ Wr,
    const float* __restrict__ Wh, const float* __restrict__ Wy,
    u16* __restrict__ Wzh, u16* __restrict__ Wzx,
    u16* __restrict__ Wrh, u16* __restrict__ Wrx,
    u16* __restrict__ Whh, u16* __restrict__ Whx, u16* __restrict__ WyB) {
  int i = blockIdx.x * 256 + threadIdx.x;
  if (i < HID * CAT) {
    int row = i / CAT, col = i - row * CAT;
    u16 vz = f2bf(Wz[i]), vr = f2bf(Wr[i]), vh = f2bf(Wh[i]);
    if (col < HID) {
      Wzh[row * HID + col] = vz;
      Wrh[row * HID + col] = vr;
      Whh[row * HID + col] = vh;
    } else {
      int c = col - HID;
      Wzx[row * EMB + c] = vz;
      Wrx[row * EMB + c] = vr;
      Whx[row * EMB + c] = vh;
    }
  }
  if (i < EMB * HID) WyB[i] = f2bf(Wy[i]);
}

// -------- phase 1 (fused, M=128): Pg = shift(word) @ Wg_x.T + bg --------
__global__ __launch_bounds__(256) void proj3_kernel(
    const float* __restrict__ word,
    const u16* __restrict__ Wzx, const u16* __restrict__ Wrx, const u16* __restrict__ Whx,
    const float* __restrict__ bz, const float* __restrict__ br, const float* __restrict__ bh,
    u16* __restrict__ Pz, u16* __restrict__ Pr, u16* __restrict__ Ph) {
  __shared__ __align__(16) u16 As[128][64 + GPAD];
  __shared__ __align__(16) u16 Bs[3][64][64 + GPAD];
  const int tid = threadIdx.x;
  const int wid = tid >> 6, lane = tid & 63;
  const int m0 = blockIdx.x * 128, n0 = blockIdx.y * 64;
  const int mw = wid * 32;  // each wave owns 32 rows x 64 cols
  const u16* __restrict__ Wx[3] = {Wzx, Wrx, Whx};
  f32x4 acc[3][2][4] = {};
  for (int k0 = 0; k0 < EMB; k0 += 64) {
#pragma unroll
    for (int it = 0; it < 8; ++it) {
      int e = (it * 256 + tid) * 4;
      int row = e >> 6, col = e & 63;
      int R = m0 + row;
      float4 a = make_float4(0.f, 0.f, 0.f, 0.f);
      if ((R & (TLEN - 1)) != 0)
        a = *reinterpret_cast<const float4*>(&word[(u64)(R - 1) * EMB + k0 + col]);
      s16x4 vv;
      vv[0] = (short)f2bf(a.x); vv[1] = (short)f2bf(a.y);
      vv[2] = (short)f2bf(a.z); vv[3] = (short)f2bf(a.w);
      *reinterpret_cast<s16x4*>(&As[row][col]) = vv;
    }
#pragma unroll
    for (int p = 0; p < 3; ++p)
#pragma unroll
      for (int it = 0; it < 2; ++it) {
        int e = (it * 256 + tid) * 8;
        int row = e >> 6, col = e & 63;
        *reinterpret_cast<bf16x8*>(&Bs[p][row][col]) =
            *reinterpret_cast<const bf16x8*>(&Wx[p][(u64)(n0 + row) * EMB + k0 + col]);
      }
    __syncthreads();
#pragma unroll
    for (int kk = 0; kk < 2; ++kk) {
      const int kb = kk * 32 + 8 * (lane >> 4);
#pragma unroll
      for (int i = 0; i < 2; ++i) {
        bf16x8 a = *reinterpret_cast<const bf16x8*>(&As[mw + i * 16 + (lane & 15)][kb]);
#pragma unroll
        for (int p = 0; p < 3; ++p)
#pragma unroll
          for (int j = 0; j < 4; ++j) {
            bf16x8 b = *reinterpret_cast<const bf16x8*>(&Bs[p][j * 16 + (lane & 15)][kb]);
            acc[p][i][j] = __builtin_amdgcn_mfma_f32_16x16x32_bf16(a, b, acc[p][i][j], 0, 0, 0);
          }
      }
    }
    __syncthreads();
  }
  u16* __restrict__ Pout[3] = {Pz, Pr, Ph};
  const float* __restrict__ bias[3] = {bz, br, bh};
#pragma unroll
  for (int p = 0; p < 3; ++p)
#pragma unroll
    for (int i = 0; i < 2; ++i)
#pragma unroll
      for (int j = 0; j < 4; ++j) {
        int col = n0 + j * 16 + (lane & 15);
        float bv = bias[p][col];
#pragma unroll
        for (int q = 0; q < 4; ++q) {
          int row = m0 + mw + i * 16 + 4 * (lane >> 4) + q;
          Pout[p][(u64)row * HID + col] = f2bf(acc[p][i][j][q] + bv);
        }
      }
}

// ---------------- phase 3 (M=128): out = H @ Wy.T + by (fp32 out) ----------------
__global__ __launch_bounds__(256) void out_gemm(const u16* __restrict__ H,
                                                const u16* __restrict__ Wy,
                                                const float* __restrict__ by,
                                                float* __restrict__ out) {
  __shared__ __align__(16) u16 As[128][64 + GPAD];
  __shared__ __align__(16) u16 Bs[64][64 + GPAD];
  const int tid = threadIdx.x;
  const int wid = tid >> 6, lane = tid & 63;
  const int m0 = blockIdx.x * 128, n0 = blockIdx.y * 64;
  const int mw = wid * 32;  // each wave: 32 rows x 64 cols
  f32x4 acc[2][4] = {};
  for (int k0 = 0; k0 < HID; k0 += 64) {
#pragma unroll
    for (int it = 0; it < 4; ++it) {
      int e = (it * 256 + tid) * 8;
      int row = e >> 6, col = e & 63;
      *reinterpret_cast<bf16x8*>(&As[row][col]) =
          *reinterpret_cast<const bf16x8*>(&H[(u64)(m0 + row) * HID + k0 + col]);
    }
#pragma unroll
    for (int it = 0; it < 2; ++it) {
      int e = (it * 256 + tid) * 8;
      int row = e >> 6, col = e & 63;
      *reinterpret_cast<bf16x8*>(&Bs[row][col]) =
          *reinterpret_cast<const bf16x8*>(&Wy[(u64)(n0 + row) * HID + k0 + col]);
    }
    __syncthreads();
#pragma unroll
    for (int kk = 0; kk < 2; ++kk) {
      const int kb = kk * 32 + 8 * (lane >> 4);
#pragma unroll
      for (int i = 0; i < 2; ++i) {
        bf16x8 a = *reinterpret_cast<const bf16x8*>(&As[mw + i * 16 + (lane & 15)][kb]);
#pragma unroll
        for (int j = 0; j < 4; ++j) {
          bf16x8 b = *reinterpret_cast<const bf16x8*>(&Bs[j * 16 + (lane & 15)][kb]);
          acc[i][j] = __builtin_amdgcn_mfma_f32_16x16x32_bf16(a, b, acc[i][j], 0, 0, 0);
        }
      }
    }
    __syncthreads();
  }
#pragma unroll
  for (int i = 0; i < 2; ++i)
#pragma unroll
    for (int j = 0; j < 4; ++j) {
      int col = n0 + j * 16 + (lane & 15);
      float bv = by[col];
#pragma unroll
      for (int q = 0; q < 4; ++q) {
        int row = m0 + mw + i * 16 + 4 * (lane >> 4) + q;
        out[(u64)row * EMB + col] = acc[i][j][q] + bv;
      }
    }
}

// ---------------- phase 2: persistent recurrent kernel (v15/v16 protocol) ----------------
__device__ __forceinline__ void poll_flags_wave(u32* gflags, u32 target) {
  const int lane = threadIdx.x & 63;
  const int active = (lane < WPG) ? 1 : 0;
  u32* addr = &gflags[(lane & (WPG - 1)) * 16];
  for (;;) {
    u32 v = target;
    if (active)
      v = __hip_atomic_load(addr, __ATOMIC_RELAXED, __HIP_MEMORY_SCOPE_AGENT);
    if (!__any((int)(v < target))) break;
  }
}

__global__ __launch_bounds__(256, 1) void gru_persistent(
    const u16* __restrict__ Wzh, const u16* __restrict__ Wrh, const u16* __restrict__ Whh,
    const u16* __restrict__ Pz, const u16* __restrict__ Pr, u16* __restrict__ PhH,
    u16* __restrict__ rhbuf, u32* flags) {
  // LDS ~34.8 KB: hx (coop-load staging, swizzled) + zL + RED.
  __shared__ __align__(16) u16 hx[16 * HX_LD];
  __shared__ __align__(16) u16 zL[16 * ZL_LD];
  __shared__ __align__(16) float RED[4 * 64 * 4];

  const int tid = threadIdx.x;
  const int wid = tid >> 6;
  const int lane = tid & 63;
  const int l15 = lane & 15;
  const int k4 = lane >> 4;  // 0..3
  const int g = blockIdx.x & (GROUPS - 1);
  const int w = blockIdx.x >> 2;  // 0..31, owns cols [32w, 32w+32)
  const int b0 = g * GB;
  const int j = wid & 1;        // 16-col tile within the 32
  const int gate = wid >> 1;    // stage A: 0 = z, 1 = r
  const int kh = wid >> 1;      // stage B: K-half
  const int colA = 32 * w + 16 * j + l15;
  const u16* __restrict__ PA = gate ? Pr : Pz;
  u32* gflags = flags + g * (WPG * 16);

  // hx XOR swizzle: element offset e in row r maps to e ^ ((r&7)<<3).
  const int sw = (l15 & 7) << 3;
  const int srow = tid >> 4;
  const int soff = (tid & 15) * 4;
  const int ssw = (srow & 7) << 3;

  // ---- weights -> registers, PINNED (asm "+v" blocks rematerialization) ----
  bf16x8 wfA[32];  // 16 cols of Wzh (waves 0-1) or Wrh (waves 2-3), full K
#pragma unroll
  for (int s = 0; s < 32; ++s)
    wfA[s] = *reinterpret_cast<const bf16x8*>(
        (gate ? Wrh : Wzh) + (u64)colA * HID + 32 * s + k4 * 8);
  bf16x8 wfB[16];  // 16 cols of Whh, K-half kh
#pragma unroll
  for (int s = 0; s < 16; ++s)
    wfB[s] = *reinterpret_cast<const bf16x8*>(
        Whh + (u64)colA * HID + kh * 512 + 32 * s + k4 * 8);
#pragma unroll
  for (int s = 0; s < 32; ++s) asm volatile("" : "+v"(wfA[s]));
#pragma unroll
  for (int s = 0; s < 16; ++s) asm volatile("" : "+v"(wfB[s]));

  // zero hx (h(-1) = 0; swizzle-invariant)
  for (int e = tid; e < 16 * HX_LD / 2; e += 256) reinterpret_cast<u32*>(hx)[e] = 0u;
  __syncthreads();

  // prefetched P values — RAW u16 (convert at use; waits sink to use point)
  u16 pAr[4], pBr[4];
#pragma unroll
  for (int q = 0; q < 4; ++q) {
    int m = 4 * k4 + q;
    pAr[q] = PA[((u64)(b0 + m) * TLEN) * HID + colA];
    pBr[q] = PhH[((u64)(b0 + m) * TLEN) * HID + colA];
  }

  float hprev[4] = {0.f, 0.f, 0.f, 0.f};  // h(t-1) at (4*k4+q, colA), ALL waves
  u32 ph = 0;

  for (int t = 0; t < TLEN; ++t) {
    // ---- cooperative load h(t-1) -> hx (batched agent u64 loads) ----
    if (t > 0) {
      const u16* src = PhH + ((u64)(b0 + srow) * TLEN + (t - 1)) * HID + soff;
      u64 tmp[16];
#pragma unroll
      for (int i = 0; i < 16; ++i) tmp[i] = ld_dc(src + i * 64);
      u16* dst = &hx[srow * HX_LD];
#pragma unroll
      for (int i = 0; i < 16; ++i)
        *reinterpret_cast<u64*>(dst + ((soff + i * 64) ^ ssw)) = tmp[i];
      __syncthreads();
    }

    // ================= phase A: z,r = sigmoid(h @ W.T + P) =================
    f32x4 acc = {0.f, 0.f, 0.f, 0.f}, acc_b = {0.f, 0.f, 0.f, 0.f};
    if (t > 0) {
#pragma unroll
      for (int s = 0; s < 32; s += 2) {
        bf16x8 a0 = *reinterpret_cast<const bf16x8*>(
            &hx[l15 * HX_LD + ((32 * s + k4 * 8) ^ sw)]);
        bf16x8 a1 = *reinterpret_cast<const bf16x8*>(
            &hx[l15 * HX_LD + ((32 * (s + 1) + k4 * 8) ^ sw)]);
        acc   = __builtin_amdgcn_mfma_f32_16x16x32_bf16(a0, wfA[s],     acc,   0, 0, 0);
        acc_b = __builtin_amdgcn_mfma_f32_16x16x32_bf16(a1, wfA[s + 1], acc_b, 0, 0, 0);
      }
    }
#pragma unroll
    for (int q = 0; q < 4; ++q) {
      int m = 4 * k4 + q;
      float pre = acc[q] + acc_b[q] + bf2f(pAr[q]);
      float sg = 1.f / (1.f + __expf(-pre));
      if (gate == 0) {
        zL[m * ZL_LD + 16 * j + l15] = f2bf(sg);
      } else {
        st_dc16(rhbuf + (u64)(g * GB + m) * HID + colA, f2bf(sg * hprev[q]));
      }
    }

    // ---- barrier A: drain-sync -> flag -> prefetch pA -> all-wave poll ----
    ++ph;
    __syncthreads();
    asm volatile("" ::: "memory");
    if (tid == w)
      __hip_atomic_store(&gflags[w * 16], ph, __ATOMIC_RELAXED, __HIP_MEMORY_SCOPE_AGENT);
    {
      int tn = (t + 1 < TLEN) ? (t + 1) : t;
#pragma unroll
      for (int q = 0; q < 4; ++q) {
        int m = 4 * k4 + q;
        pAr[q] = PA[((u64)(b0 + m) * TLEN + tn) * HID + colA];  // raw, no wait
      }
    }
    poll_flags_wave(gflags, ph);
    asm volatile("" ::: "memory");

    // ---- cooperative load rh -> hx (each wave self-released by its poll) ----
    {
      const u16* src = rhbuf + (u64)(g * GB + srow) * HID + soff;
      u64 tmp[16];
#pragma unroll
      for (int i = 0; i < 16; ++i) tmp[i] = ld_dc(src + i * 64);
      u16* dst = &hx[srow * HX_LD];
#pragma unroll
      for (int i = 0; i < 16; ++i)
        *reinterpret_cast<u64*>(dst + ((soff + i * 64) ^ ssw)) = tmp[i];
      __syncthreads();
    }

    // ========= phase B: htilde = tanh(rh @ Whh.T + Ph); h update =========
    f32x4 acc2 = {0.f, 0.f, 0.f, 0.f}, acc2b = {0.f, 0.f, 0.f, 0.f};
#pragma unroll
    for (int s = 0; s < 16; s += 2) {
      bf16x8 a0 = *reinterpret_cast<const bf16x8*>(
          &hx[l15 * HX_LD + ((kh * 512 + 32 * s + k4 * 8) ^ sw)]);
      bf16x8 a1 = *reinterpret_cast<const bf16x8*>(
          &hx[l15 * HX_LD + ((kh * 512 + 32 * (s + 1) + k4 * 8) ^ sw)]);
      acc2  = __builtin_amdgcn_mfma_f32_16x16x32_bf16(a0, wfB[s],     acc2,  0, 0, 0);
      acc2b = __builtin_amdgcn_mfma_f32_16x16x32_bf16(a1, wfB[s + 1], acc2b, 0, 0, 0);
    }
#pragma unroll
    for (int q = 0; q < 4; ++q) acc2[q] += acc2b[q];
    // exchange K-half partials; ALL waves compute identical h (add commutes)
    *reinterpret_cast<f32x4*>(&RED[(wid * 64 + lane) * 4]) = acc2;
    __syncthreads();
    {
      f32x4 part = *reinterpret_cast<const f32x4*>(&RED[((wid ^ 2) * 64 + lane) * 4]);
#pragma unroll
      for (int q = 0; q < 4; ++q) {
        int m = 4 * k4 + q;
        float pre = acc2[q] + part[q] + bf2f(pBr[q]);
        float e2 = __expf(2.f * pre);
        float th = 1.f - 2.f / (e2 + 1.f);  // tanh, inf-safe
        float zq = bf2f(zL[m * ZL_LD + 16 * j + l15]);
        float hn = (1.f - zq) * hprev[q] + zq * th;
        hprev[q] = hn;
        if (wid < 2)  // direct store h(t) -> PhH[t] (in-place over Ph)
          st_dc16(PhH + ((u64)(b0 + m) * TLEN + t) * HID + colA, f2bf(hn));
      }
    }

    // ---- barrier B: drain-sync -> flag -> prefetch pB -> all-wave poll ----
    ++ph;
    __syncthreads();
    asm volatile("" ::: "memory");
    if (tid == w)
      __hip_atomic_store(&gflags[w * 16], ph, __ATOMIC_RELAXED, __HIP_MEMORY_SCOPE_AGENT);
    {
      int tn = (t + 1 < TLEN) ? (t + 1) : t;
#pragma unroll
      for (int q = 0; q < 4; ++q) {
        int m = 4 * k4 + q;
        pBr[q] = PhH[((u64)(b0 + m) * TLEN + tn) * HID + colA];  // raw, no wait
      }
    }
    poll_flags_wave(gflags, ph);
    asm volatile("" ::: "memory");
  }
}

// ---------------- host ----------------
extern "C" void kernel_launch(void* const* d_in, const int* in_sizes, int n_in,
                              void* d_out, int out_size, void* d_ws, size_t ws_size,
                              hipStream_t stream) {
  const float* word = (const float*)d_in[0];
  const float* Wz = (const float*)d_in[1];
  const float* bz = (const float*)d_in[2];
  const float* Wr = (const float*)d_in[3];
  const float* br = (const float*)d_in[4];
  const float* Wh = (const float*)d_in[5];
  const float* bh = (const float*)d_in[6];
  const float* Wy = (const float*)d_in[7];
  const float* by = (const float*)d_in[8];
  float* out = (float*)d_out;
  (void)in_sizes; (void)n_in; (void)out_size; (void)ws_size;

  char* ws = (char*)d_ws;
  size_t off = 0;
  auto alloc = [&](size_t bytes) {
    char* p = ws + off;
    off += (bytes + 255) & ~(size_t)255;
    return p;
  };
  u32* flags = (u32*)alloc(GROUPS * WPG * 16 * sizeof(u32));  // 8 KB
  u16* WzhB = (u16*)alloc((size_t)HID * HID * 2);
  u16* WrhB = (u16*)alloc((size_t)HID * HID * 2);
  u16* WhhB = (u16*)alloc((size_t)HID * HID * 2);
  u16* WzxB = (u16*)alloc((size_t)HID * EMB * 2);
  u16* WrxB = (u16*)alloc((size_t)HID * EMB * 2);
  u16* WhxB = (u16*)alloc((size_t)HID * EMB * 2);
  u16* WyB  = (u16*)alloc((size_t)EMB * HID * 2);
  u16* Pr   = (u16*)alloc((size_t)BATCHN * TLEN * HID * 2);
  u16* PhH  = (u16*)alloc((size_t)BATCHN * TLEN * HID * 2);
  u16* rhbuf = (u16*)alloc((size_t)GROUPS * GB * HID * 2);
  // total ws use ~138 MiB
  u16* Pz = (u16*)d_out;  // overlay: 32768x1024 bf16 == 32768x512 fp32; dead
                          // before out_gemm overwrites d_out.

  hipMemsetAsync(flags, 0, GROUPS * WPG * 16 * sizeof(u32), stream);

  convert_all<<<(HID * CAT + 255) / 256, 256, 0, stream>>>(
      Wz, Wr, Wh, Wy, WzhB, WzxB, WrhB, WrxB, WhhB, WhxB, WyB);

  proj3_kernel<<<dim3(256, 16), 256, 0, stream>>>(word, WzxB, WrxB, WhxB,
                                                  bz, br, bh, Pz, Pr, PhH);

  gru_persistent<<<dim3(GROUPS * WPG), dim3(256), 0, stream>>>(WzhB, WrhB, WhhB, Pz, Pr, PhH,
                                                               rhbuf, flags);

  out_gemm<<<dim3(256, 8), 256, 0, stream>>>(PhH, WyB, by, out);
}